// Round 11
// baseline (372.580 us; speedup 1.0000x reference)
//
#include <hip/hip_runtime.h>
#include <cstdint>
#include <cstddef>

namespace {

constexpr int Bn   = 8;
constexpr int Cc   = 128;
constexpr int Hh   = 56;
constexpr int Ww   = 56;
constexpr int OUTC = 128;
constexpr int NTAP = 9;
constexpr int HW   = 3136;
constexpr int NPOS = Bn * HW;      // 25088
constexpr int KDIM = 1152;         // Cc*NTAP

constexpr int PT   = 32;           // positions per block
constexpr int CCH  = 64;           // channels per GEMM chunk (2 chunks)
constexpr int KC   = CCH * NTAP;   // 576
constexpr int LROW = 584;          // ushort row stride (1168B, 16B-aligned)

typedef __attribute__((ext_vector_type(8))) short  short8v;
typedef __attribute__((ext_vector_type(4))) short  short4v;
typedef __attribute__((ext_vector_type(4))) float  float4v;

__device__ __forceinline__ unsigned short f2bf(float f) {
    union { float f; uint32_t u; } v; v.f = f;
    const uint32_t u = v.u;
    return (unsigned short)((u + 0x7fffu + ((u >> 16) & 1u)) >> 16);  // RNE
}
__device__ __forceinline__ float bf2f(unsigned short us) {
    union { uint32_t u; float f; } v; v.u = (uint32_t)us << 16;
    return v.f;
}

// ---------------------------------------------------------------------------
// Prep (unchanged): (a) cwb bf16, k' = cc*576 + n*64 + cl
//                   (b) owp fp32 [c][m*9+tap]
//                   (c) xt bf16 channel-last [b][ij][c]
// ---------------------------------------------------------------------------
__global__ __launch_bounds__(256) void prep_kernel(
        const float* __restrict__ cw, const float* __restrict__ ow,
        const float* __restrict__ x, unsigned short* __restrict__ cwb,
        float* __restrict__ owp, unsigned short* __restrict__ xt) {
    const int blk = blockIdx.x;
    const int t = threadIdx.x;
    if (blk < 576) {                               // weights: 128*1152 elems
        const int i = blk * 256 + t;
        const int o = i / KDIM, k = i % KDIM;
        const int cc = k / KC, r = k % KC, n = r >> 6, cl = r & 63;
        cwb[i] = f2bf(cw[o * KDIM + (cc * CCH + cl) * NTAP + n]);
        return;
    }
    if (blk < 657) {                               // owp: 128*162 = 20736 elems
        const int i = (blk - 576) * 256 + t;
        const int c = i / 162, r = i % 162;        // r = m*9+tap
        owp[i] = ow[(r / 9) * KDIM + c * NTAP + (r % 9)];
        return;
    }
    // transpose: 392 blocks, 64 pos x 128 ch each
    const int blk2 = blk - 657;
    const int b = blk2 & 7;
    const int ijb = (blk2 >> 3) * 64;
    const int lp = t & 63, cg = t >> 6;
    const float* xb = x + (size_t)b * Cc * HW + ijb + lp;
    unsigned short* xr = xt + ((size_t)b * HW + ijb + lp) * Cc + cg * 32;
#pragma unroll
    for (int c8 = 0; c8 < 4; ++c8) {
        short8v sv;
#pragma unroll
        for (int u = 0; u < 8; ++u)
            sv[u] = (short)f2bf(xb[(size_t)(cg * 32 + c8 * 8 + u) * HW]);
        *(short8v*)(xr + c8 * 8) = sv;
    }
}

// ---------------------------------------------------------------------------
// Fused kernel:
//   phase0: offset conv (exact fp32, R2-lineage 16-c slice chains, tree-of-8
//           reduce) -> praw[m][pos] in LDS.  red[] overlays xoffB (union).
//   phase1: exact fp32 trunc-bilinear params from praw -> pgS/poS.
//   phase2: branchless bf16 gather staging + MFMA GEMM (byte-identical to
//           the R9-proven kernel).
// 784 blocks, XCD b-affinity (b = blk&7): x[b] + xt[b] L2-resident.
// LDS 46.6 KB -> 3 blocks/CU (same residency as R9's K2).
// ---------------------------------------------------------------------------
__global__ __launch_bounds__(256, 3) void deform_fused_kernel(
        const float* __restrict__ x, const unsigned short* __restrict__ xt,
        const unsigned short* __restrict__ cwb, const float* __restrict__ owp,
        const float* __restrict__ ob, float* __restrict__ out) {
    __shared__ __align__(16) char ldsu[PT * LROW * 2];   // 37.4 KB union
    __shared__ float4v pgS[PT * NTAP];             // {g2,g3,g0,g1}  4.6 KB
    __shared__ int2    poS[PT * NTAP];             // {o2|o3<<16, o0|o1<<16} 2.3 KB
    __shared__ float   praw[18 * PT];              // p[m][pos] 2.3 KB
    unsigned short* xoffB = (unsigned short*)ldsu; // phase2 view
    float* red = (float*)ldsu;                     // phase0 view: [g*576 + lp*18 + m]

    const int t    = threadIdx.x;
    const int lane = t & 63;
    const int mm   = lane & 15, quad = lane >> 4;
    const int wv   = t >> 6;
    const int lp   = t & 31, grp = t >> 5;         // pos, 8-ch/16-c group
    const int blk  = blockIdx.x;
    const int b    = blk & 7;                      // XCD affinity
    const int ijb  = (blk >> 3) * PT;
    const unsigned short* xtb = xt + (size_t)b * HW * Cc;

    // ================= phase0: offset conv -> praw =================
    {
        const int ij0 = ijb + lp;
        const int i0 = ij0 / Ww, j0 = ij0 % Ww;
        const float* xb = x + (size_t)b * Cc * HW;
        float acc[18];
#pragma unroll
        for (int m = 0; m < 18; ++m) acc[m] = 0.f;
#pragma unroll 2
        for (int cc = 0; cc < 16; ++cc) {
            const int c = grp * 16 + cc;
            const float* xc = xb + (size_t)c * HW;
            float xv[9];
#pragma unroll
            for (int ky = 0; ky < 3; ++ky) {
                const int y = i0 + ky - 1;
                const bool yv = (unsigned)y < (unsigned)Hh;
#pragma unroll
                for (int kx = 0; kx < 3; ++kx) {
                    const int xx = j0 + kx - 1;
                    xv[ky * 3 + kx] = (yv && (unsigned)xx < (unsigned)Ww) ? xc[y * Ww + xx] : 0.f;
                }
            }
            const float* wp = owp + c * 162;       // contiguous 648 B per c
#pragma unroll
            for (int m = 0; m < 18; ++m) {
#pragma unroll
                for (int tap = 0; tap < 9; ++tap)
                    acc[m] = fmaf(wp[m * 9 + tap], xv[tap], acc[m]);
            }
        }
#pragma unroll
        for (int m = 0; m < 18; ++m) red[grp * 576 + lp * 18 + m] = acc[m];
    }
    __syncthreads();

    for (int e = t; e < 576; e += 256) {           // e = pos*18 + m
        const int lpe = e / 18, m = e % 18;
        const float s01 = red[0 * 576 + e] + red[1 * 576 + e];
        const float s23 = red[2 * 576 + e] + red[3 * 576 + e];
        const float s45 = red[4 * 576 + e] + red[5 * 576 + e];
        const float s67 = red[6 * 576 + e] + red[7 * 576 + e];
        const float s = (s01 + s23) + (s45 + s67);
        const int ije = ijb + lpe;
        const float base = (m < 9) ? (float)(ije / Ww + m / 3)
                                   : (float)(ije % Ww + (m - 9) % 3);
        praw[m * PT + lpe] = base + (s + ob[m]);
    }
    __syncthreads();

    // ================= phase1: params (exact fp32 chain) =================
    for (int e = t; e < PT * NTAP; e += 256) {
        const int n = e >> 5, lpe = e & 31;
        const float py = praw[n * PT + lpe];
        const float px = praw[(9 + n) * PT + lpe];
        const float q0y = floorf(py), q0x = floorf(px);
        const float lty = fminf(fmaxf(q0y, 0.f), 57.f);
        const float ltx = fminf(fmaxf(q0x, 0.f), 57.f);
        const float rby = fminf(fmaxf(q0y + 1.f, 0.f), 57.f);
        const float rbx = fminf(fmaxf(q0x + 1.f, 0.f), 57.f);
        const float pyc = fminf(fmaxf(py, 0.f), 57.f);
        const float pxc = fminf(fmaxf(px, 0.f), 57.f);
        float g0 = (1.f - (pyc - lty)) * truncf(1.f - (pxc - ltx));   // lt
        float g1 = (1.f - (rby - pyc)) * truncf(1.f - (rbx - pxc));   // rb
        float g2 = (1.f - (pyc - lty)) * (1.f - (rbx - pxc));         // lb (lty,rbx)
        float g3 = (1.f - (rby - pyc)) * (1.f - (pxc - ltx));         // rt (rby,ltx)
        const int y0 = (int)lty - 1, x0 = (int)ltx - 1;
        const int y1 = (int)rby - 1, x1 = (int)rbx - 1;
        const bool v0y = (unsigned)y0 < (unsigned)Hh, v0x = (unsigned)x0 < (unsigned)Ww;
        const bool v1y = (unsigned)y1 < (unsigned)Hh, v1x = (unsigned)x1 < (unsigned)Ww;
        int o0 = y0 * Ww + x0, o1 = y1 * Ww + x1, o2 = y0 * Ww + x1, o3 = y1 * Ww + x0;
        if (!(v0y && v0x)) { o0 = 0; g0 = 0.f; }
        if (!(v1y && v1x)) { o1 = 0; g1 = 0.f; }
        if (!(v0y && v1x)) { o2 = 0; g2 = 0.f; }
        if (!(v1y && v0x)) { o3 = 0; g3 = 0.f; }
        pgS[e] = (float4v){ g2, g3, g0, g1 };
        poS[e] = make_int2((o2 & 0xffff) | (o3 << 16), (o0 & 0xffff) | (o1 << 16));
    }

    float4v acc[2][2] = { { {0.f,0.f,0.f,0.f}, {0.f,0.f,0.f,0.f} },
                          { {0.f,0.f,0.f,0.f}, {0.f,0.f,0.f,0.f} } };
    __syncthreads();

    // ================= phase2: staging + MFMA GEMM (R9-proven) =============
    for (int cc = 0; cc < 2; ++cc) {
        if (cc) __syncthreads();
        // ---- branchless staging: 9 taps x (4 gathers of 8ch) ----
        const int cbase = cc * CCH + grp * 8;
#pragma unroll
        for (int n = 0; n < 9; ++n) {
            const float4v G = pgS[n * 32 + lp];
            const int2  O = poS[n * 32 + lp];
            const short8v a2 = *(const short8v*)(xtb + (size_t)(O.x & 0xffff) * Cc + cbase);
            const short8v a3 = *(const short8v*)(xtb + (size_t)((O.x >> 16) & 0xffff) * Cc + cbase);
            const short8v a0 = *(const short8v*)(xtb + (size_t)(O.y & 0xffff) * Cc + cbase);
            const short8v a1 = *(const short8v*)(xtb + (size_t)((O.y >> 16) & 0xffff) * Cc + cbase);
            short8v sv;
#pragma unroll
            for (int u = 0; u < 8; ++u) {
                float v = G.x * bf2f((unsigned short)a2[u]);
                v = fmaf(G.y, bf2f((unsigned short)a3[u]), v);
                v = fmaf(G.z, bf2f((unsigned short)a0[u]), v);
                v = fmaf(G.w, bf2f((unsigned short)a1[u]), v);
                sv[u] = (short)f2bf(v);
            }
            *(short8v*)&xoffB[lp * LROW + n * CCH + grp * 8] = sv;
        }
        __syncthreads();

        // ---- MFMA GEMM: 18 ks-steps, B straight from L2 ----
        const unsigned short* bw0 = cwb + (size_t)(wv * 32 + mm) * KDIM + cc * KC;
        const unsigned short* bw1 = bw0 + 16 * KDIM;
        const unsigned short* ap0 = &xoffB[mm * LROW + quad * 8];
#pragma unroll 3
        for (int ks = 0; ks < KC / 32; ++ks) {
            const int kl = ks * 32;
            const short8v b0 = *(const short8v*)(bw0 + kl + quad * 8);
            const short8v b1 = *(const short8v*)(bw1 + kl + quad * 8);
#pragma unroll
            for (int pt = 0; pt < 2; ++pt) {
                const unsigned short* ap = ap0 + pt * 16 * LROW + kl;
                const short4v alo = *(const short4v*)ap;
                const short4v ahi = *(const short4v*)(ap + 4);
                const short8v a = __builtin_shufflevector(alo, ahi, 0, 1, 2, 3, 4, 5, 6, 7);
                acc[pt][0] = __builtin_amdgcn_mfma_f32_16x16x32_bf16(a, b0, acc[pt][0], 0, 0, 0);
                acc[pt][1] = __builtin_amdgcn_mfma_f32_16x16x32_bf16(a, b1, acc[pt][1], 0, 0, 0);
            }
        }
    }

    // ---- epilogue (layout verified R2/R4/R5) ----
    float* ob0 = out + (size_t)(b * OUTC + wv * 32 + mm) * HW + ijb + quad * 4;
#pragma unroll
    for (int pt = 0; pt < 2; ++pt) {
        *(float4v*)(ob0 + pt * 16) = acc[pt][0];
        *(float4v*)(ob0 + (size_t)16 * HW + pt * 16) = acc[pt][1];
    }
}

}  // namespace

extern "C" void kernel_launch(void* const* d_in, const int* in_sizes, int n_in,
                              void* d_out, int out_size, void* d_ws, size_t ws_size,
                              hipStream_t stream) {
    const float* x  = (const float*)d_in[0];   // (8,128,56,56)
    const float* ow = (const float*)d_in[1];   // (18,128,3,3)
    const float* ob = (const float*)d_in[2];   // (18,)
    const float* cw = (const float*)d_in[3];   // (128,128,3,3)
    float* out = (float*)d_out;                // (8,128,56,56)

    char* wsp = (char*)d_ws;
    unsigned short* cwb = (unsigned short*)wsp;                 //   294,912 B
    float* owp = (float*)(wsp + 294912);                        //    82,944 B
    unsigned short* xt = (unsigned short*)(wsp + 377856);       // 6,422,528 B
                                                                // total 6.80 MB

    prep_kernel<<<576 + 81 + 392, 256, 0, stream>>>(cw, ow, x, cwb, owp, xt);
    deform_fused_kernel<<<NPOS / PT, 256, 0, stream>>>(x, xt, cwb, owp, ob, out);
}